// Round 8
// baseline (355.280 us; speedup 1.0000x reference)
//
#include <hip/hip_runtime.h>
#include <math.h>

#define DIM   4096
#define BLKT  256           // 4 waves per block; 8 amplitudes (v2f) per thread
#define NPAR  144

typedef float v2f __attribute__((ext_vector_type(2)));

// ---------------------------------------------------------------------------
// Element split across a block PAIR: 12 canonical bits = 3 reg + 6 lane
// (tid 0..5) + 2 wave (tid 6,7) + 1 block bit. 12-epoch/layer schedule
// (validated R6/R7). Pin-runs: A-epochs {0,1,2,10,11}: wav {6,7}, blk 8;
// B-epochs {3..9}: wav {2,3}, blk 4. 29 transitions are wave-local LDS
// restages (no barrier, in-order LDS pipe, b128). 6 transitions change the
// block bit -> global exchange through d_ws with release/acquire flags.
// ---------------------------------------------------------------------------
struct Ph { int reg[3]; int wav[2]; int blk; };

constexpr int REGS[12][3] = {
  {11,0,1},{1,2,3},{3,4,5},{5,6,7},{7,8,9},{9,10,11},
  {11,0,1},{9,10,11},{7,8,9},{5,6,7},{3,4,5},{1,2,3}};

constexpr bool isA(int e) { return e <= 2 || e >= 10; }

constexpr Ph phaseAt(int i) {          // i = 1..36 epochs; 37 = output phase
  Ph p = {};
  if (i == 37) { p.reg[0]=0; p.reg[1]=1; p.reg[2]=2; p.wav[0]=9; p.wav[1]=10; p.blk=8; return p; }
  int e = (i - 1) % 12;
  p.reg[0]=REGS[e][0]; p.reg[1]=REGS[e][1]; p.reg[2]=REGS[e][2];
  if (isA(e)) { p.wav[0]=6; p.wav[1]=7; p.blk=8; }
  else        { p.wav[0]=2; p.wav[1]=3; p.blk=4; }
  return p;
}
constexpr bool exchq(int T) { return T <= 35 && ((T % 12) == 3 || (T % 12) == 10); }
constexpr int  exchOrd(int T) { return (T / 12) * 2 + (((T % 12) == 3) ? 0 : 1); }

constexpr bool inArr(const int* a, int n, int b) {
  for (int i = 0; i < n; ++i) if (a[i] == b) return true;
  return false;
}
constexpr int idxOf3(const int* a, int v) {
  for (int j = 0; j < 3; ++j) if (a[j] == v) return j;
  return -1;
}

struct TMapL { unsigned pk[8]; unsigned short so[8]; unsigned short rn[8]; int js, jn; bool ok; };
struct TMapX { unsigned pkw[9]; unsigned short so[8]; int js; int rd[8]; bool ok; };

// Local (and final cross-wave) LDS map: 11-bit slot (blk excluded).
// Row 0 = shared reg bit (b128 pairing both sides); rows 1..3 = 3 lane bits
// common to both phases (bank-conflict-free b128); local: wave bits at rows
// 9,10 (private 4 KB/wave region); identities fill the rest. Rank-checked.
constexpr TMapL buildL(Ph o, Ph n, bool crossWave) {
  TMapL R = {}; R.ok = true;
  int sh = -1;
  for (int j = 0; j < 3; ++j) if (inArr(n.reg, 3, o.reg[j])) { sh = o.reg[j]; break; }
  if (sh < 0) { R.ok = false; return R; }
  R.js = idxOf3(o.reg, sh); R.jn = idxOf3(n.reg, sh);
  bool lo[12] = {}, ln[12] = {};
  for (int b = 0; b < 12; ++b) {
    lo[b] = b != o.blk && !inArr(o.reg,3,b) && !inArr(o.wav,2,b);
    ln[b] = b != n.blk && !inArr(n.reg,3,b) && !inArr(n.wav,2,b);
  }
  if (o.blk != n.blk) { R.ok = false; return R; }
  int col[12] = {};
  bool used[12] = {};
  col[sh] = 1; used[sh] = true;
  int row = 1;
  for (int b = 0; b < 12 && row < 4; ++b)
    if (lo[b] && ln[b] && !used[b]) { col[b] = 1 << row; used[b] = true; ++row; }
  if (row != 4) { R.ok = false; return R; }
  if (!crossWave) {
    if (used[o.wav[0]] || used[o.wav[1]]) { R.ok = false; return R; }
    col[o.wav[0]] = 1 << 9; col[o.wav[1]] = 1 << 10;
    used[o.wav[0]] = used[o.wav[1]] = true;
  }
  int idrow = 4;
  for (int b = 0; b < 12; ++b)
    if (b != o.blk && !used[b]) { col[b] = 1 << idrow; ++idrow; used[b] = true; }
  if (idrow != (crossWave ? 11 : 9)) { R.ok = false; return R; }
  {   // rank-11 over the 11 non-blk columns
    int pv[12] = {}, pb[12] = {}; int nr = 0;
    for (int b = 0; b < 12; ++b) {
      if (b == o.blk) continue;
      int v = col[b];
      for (int k = 0; k < nr; ++k) if (v & pb[k]) v ^= pv[k];
      if (v) { pb[nr] = v & (-v); pv[nr] = v; ++nr; }
    }
    if (nr != 11) { R.ok = false; return R; }
  }
  int Lo[6] = {}, Ln[6] = {}; int i0 = 0, i1 = 0;
  for (int b = 0; b < 12; ++b) { if (lo[b]) Lo[i0++] = b; if (ln[b]) Ln[i1++] = b; }
  if (i0 != 6 || i1 != 6) { R.ok = false; return R; }
  for (int i = 0; i < 8; ++i) {
    unsigned po = (i < 6) ? (unsigned)col[Lo[i]] : (unsigned)col[o.wav[i-6]];
    unsigned pn = (i < 6) ? (unsigned)col[Ln[i]] : (unsigned)col[n.wav[i-6]];
    R.pk[i] = (po * 8u) | ((pn * 8u) << 16);
  }
  for (int r = 0; r < 8; ++r) {
    int a = 0, c = 0;
    for (int j = 0; j < 3; ++j)
      if ((r >> j) & 1) { a ^= col[o.reg[j]]; c ^= col[n.reg[j]]; }
    R.so[r] = (unsigned short)(a * 8);
    R.rn[r] = (unsigned short)(c * 8);
  }
  return R;
}

// Exchange map: ws slot (12 bits) laid out in NEW order so reads are linear:
// [0]=shared reg, [1,2]=other new regs (ascending), [3..8]=new lanes (asc),
// [9,10]=new waves, [11]=new block bit. Writer scatters; reader reads its
// contiguous 16 KB half at h*16K + tid*64.
constexpr TMapX buildX(Ph o, Ph n) {
  TMapX R = {}; R.ok = true;
  int sh = -1;
  for (int j = 0; j < 3; ++j) if (inArr(n.reg, 3, o.reg[j])) { sh = o.reg[j]; break; }
  if (sh < 0) { R.ok = false; return R; }
  R.js = idxOf3(o.reg, sh);
  int col[12] = {};
  col[sh] = 1;
  { int bit = 1;
    for (int j = 0; j < 3; ++j) { int c = n.reg[j]; if (c != sh) { } }
    // other new regs ascending
    for (int c = 0; c < 12; ++c)
      if (inArr(n.reg,3,c) && c != sh) { col[c] = 1 << bit; ++bit; }
    if (bit != 3) { R.ok = false; return R; }
  }
  { int bit = 3;
    for (int c = 0; c < 12; ++c) {
      bool lane = c != n.blk && !inArr(n.reg,3,c) && !inArr(n.wav,2,c);
      if (lane) { col[c] = 1 << bit; ++bit; }
    }
    if (bit != 9) { R.ok = false; return R; }
  }
  col[n.wav[0]] = 1 << 9; col[n.wav[1]] = 1 << 10; col[n.blk] = 1 << 11;
  {   // rank-12
    int pv[12] = {}, pb[12] = {}; int nr = 0;
    for (int b = 0; b < 12; ++b) {
      int v = col[b];
      for (int k = 0; k < nr; ++k) if (v & pb[k]) v ^= pv[k];
      if (v) { pb[nr] = v & (-v); pv[nr] = v; ++nr; }
    }
    if (nr != 12) { R.ok = false; return R; }
  }
  int Lo[6] = {}; int i0 = 0;
  for (int b = 0; b < 12; ++b)
    if (b != o.blk && !inArr(o.reg,3,b) && !inArr(o.wav,2,b)) Lo[i0++] = b;
  if (i0 != 6) { R.ok = false; return R; }
  for (int i = 0; i < 6; ++i) R.pkw[i] = (unsigned)col[Lo[i]] * 8u;
  R.pkw[6] = (unsigned)col[o.wav[0]] * 8u;
  R.pkw[7] = (unsigned)col[o.wav[1]] * 8u;
  R.pkw[8] = (unsigned)col[o.blk] * 8u;
  for (int r = 0; r < 8; ++r) {
    int a = 0;
    for (int j = 0; j < 3; ++j) if ((r >> j) & 1) a ^= col[o.reg[j]];
    R.so[r] = (unsigned short)(a * 8);
  }
  // reader slot -> new reg index
  int oth[2] = {}; int k = 0;
  for (int c = 0; c < 12; ++c) if (inArr(n.reg,3,c) && c != sh) oth[k++] = c;
  int jn = idxOf3(n.reg, sh);
  int j1 = idxOf3(n.reg, oth[0]), j2 = idxOf3(n.reg, oth[1]);
  for (int s = 0; s < 8; ++s)
    R.rd[s] = (((s >> 0) & 1) << jn) | (((s >> 1) & 1) << j1) | (((s >> 2) & 1) << j2);
  return R;
}

struct AllMaps { TMapL lt[37]; TMapX xt[6]; bool ok; };
constexpr AllMaps buildAll() {
  AllMaps A = {}; A.ok = true;
  for (int T = 1; T <= 36; ++T) {
    if (exchq(T)) {
      TMapX x = buildX(phaseAt(T), phaseAt(T + 1));
      A.xt[exchOrd(T)] = x; A.ok = A.ok && x.ok;
      A.lt[T].ok = true;
    } else {
      A.lt[T] = buildL(phaseAt(T), phaseAt(T + 1), T == 36);
      A.ok = A.ok && A.lt[T].ok;
    }
  }
  return A;
}
constexpr AllMaps AM = buildAll();
static_assert(AM.ok, "map construction failed");

// ---------------- gates on the 8-amplitude register file --------------------
template<int J>
__device__ __forceinline__ void ry8(v2f (&z)[8], v2f a) {
  const float c = a.x, s = a.y;
  #pragma unroll
  for (int p = 0; p < 4; ++p) {
    const int r0 = ((p & ~((1 << J) - 1)) << 1) | (p & ((1 << J) - 1));
    const int r1 = r0 | (1 << J);
    v2f u = z[r0], v = z[r1];
    z[r0] = c * u - s * v;
    z[r1] = s * u + c * v;
  }
}
template<int JC, int JT>
__device__ __forceinline__ void crx8(v2f (&z)[8], v2f a) {
  const float c = a.x, s = a.y;
  constexpr int MC = 1 << JC, MT = 1 << JT;
  constexpr int mlo = MC < MT ? MC : MT;
  constexpr int mhi = MC < MT ? MT : MC;
  #pragma unroll
  for (int p = 0; p < 2; ++p) {
    int q = ((p & ~(mlo - 1)) << 1) | (p & (mlo - 1));
    q = ((q & ~(mhi - 1)) << 1) | (q & (mhi - 1));
    const int r0 = q | MC, r1 = r0 | MT;
    v2f u = z[r0], v = z[r1];
    v2f n0, n1;
    n0.x = c * u.x + s * v.y;
    n0.y = c * u.y - s * v.x;
    n1.x = c * v.x + s * u.y;
    n1.y = c * v.y - s * u.x;
    z[r0] = n0; z[r1] = n1;
  }
}

// Epoch gate lists — verbatim from the R6/R7-validated schedule.
template<int E>
__device__ __forceinline__ void gates(v2f (&z)[8], const v2f* ang, int base) {
  auto A = [&](int k) { return ang[base + k]; };
  if constexpr (E == 0)      { ry8<0>(z,A(0));  ry8<1>(z,A(11)); ry8<2>(z,A(10));
                               crx8<1,0>(z,A(12)); crx8<2,1>(z,A(13)); }
  else if constexpr (E == 1) { ry8<1>(z,A(9));  ry8<2>(z,A(8));
                               crx8<1,0>(z,A(14)); crx8<2,1>(z,A(15)); }
  else if constexpr (E == 2) { ry8<1>(z,A(7));  ry8<2>(z,A(6));
                               crx8<1,0>(z,A(16)); crx8<2,1>(z,A(17)); }
  else if constexpr (E == 3) { ry8<1>(z,A(5));  ry8<2>(z,A(4));
                               crx8<1,0>(z,A(18)); crx8<2,1>(z,A(19)); }
  else if constexpr (E == 4) { ry8<1>(z,A(3));  ry8<2>(z,A(2));
                               crx8<1,0>(z,A(20)); crx8<2,1>(z,A(21)); }
  else if constexpr (E == 5) { ry8<1>(z,A(1));
                               crx8<1,0>(z,A(22)); crx8<2,1>(z,A(23)); }
  else if constexpr (E == 6) { ry8<0>(z,A(24)); ry8<1>(z,A(35)); ry8<2>(z,A(34));
                               crx8<1,2>(z,A(36)); crx8<0,1>(z,A(37)); }
  else if constexpr (E == 7) { ry8<0>(z,A(26)); ry8<1>(z,A(25));
                               crx8<1,2>(z,A(38)); crx8<0,1>(z,A(39)); }
  else if constexpr (E == 8) { ry8<0>(z,A(28)); ry8<1>(z,A(27));
                               crx8<1,2>(z,A(40)); crx8<0,1>(z,A(41)); }
  else if constexpr (E == 9) { ry8<0>(z,A(30)); ry8<1>(z,A(29));
                               crx8<1,2>(z,A(42)); crx8<0,1>(z,A(43)); }
  else if constexpr (E == 10){ ry8<0>(z,A(32)); ry8<1>(z,A(31));
                               crx8<1,2>(z,A(44)); crx8<0,1>(z,A(45)); }
  else                       { ry8<1>(z,A(33));
                               crx8<1,2>(z,A(46)); crx8<0,1>(z,A(47)); }
}

// Wave-local LDS restage: in-order LDS pipe per wave => no waitcnt, no
// barrier (R7-validated). Private 4 KB region per wave for ALL local
// transitions in a pin-run; runs separated by exchange barriers.
template<int T>
__device__ __forceinline__ void restL(v2f (&z)[8], int tid, char* buf) {
  constexpr TMapL M = AM.lt[T];
  constexpr int JS = M.js, JN = M.jn;
  unsigned acc = 0;
  #pragma unroll
  for (int i = 0; i < 8; ++i)
    acc ^= (unsigned)(-((tid >> i) & 1)) & M.pk[i];
  const unsigned bo = acc & 0xffffu;
  const unsigned bn = acc >> 16;
  #pragma unroll
  for (int r = 0; r < 8; ++r) {
    if (r & (1 << JS)) continue;
    v2f z0 = z[r], z1 = z[r | (1 << JS)];
    float4 w; w.x = z0.x; w.y = z0.y; w.z = z1.x; w.w = z1.y;
    *(float4*)(buf + (bo ^ M.so[r])) = w;
  }
  asm volatile("" ::: "memory");
  #pragma unroll
  for (int r = 0; r < 8; ++r) {
    if (r & (1 << JN)) continue;
    float4 w = *(const float4*)(buf + (bn ^ M.rn[r]));
    v2f z0, z1;
    z0.x = w.x; z0.y = w.y; z1.x = w.z; z1.y = w.w;
    z[r] = z0; z[r | (1 << JN)] = z1;
  }
}

#define FLAG_MAGIC 0x0C0FFEE0

// Global exchange between the two blocks of an element pair.
template<int T>
__device__ __forceinline__ void exch(v2f (&z)[8], int tid, int h, int b,
                                     char* wsd, int* wsf) {
  constexpr int K = exchOrd(T);
  constexpr TMapX M = AM.xt[K];
  constexpr int JS = M.js;
  unsigned acc = 0;
  #pragma unroll
  for (int i = 0; i < 8; ++i)
    acc ^= (unsigned)(-((tid >> i) & 1)) & M.pkw[i];
  acc ^= (unsigned)(-h) & M.pkw[8];
  char* bufk = wsd + (size_t)(K * 128 + b) * 32768;
  #pragma unroll
  for (int r = 0; r < 8; ++r) {
    if (r & (1 << JS)) continue;
    v2f z0 = z[r], z1 = z[r | (1 << JS)];
    float4 w; w.x = z0.x; w.y = z0.y; w.z = z1.x; w.w = z1.y;
    *(float4*)(bufk + (acc ^ M.so[r])) = w;
  }
  __threadfence();
  __syncthreads();
  int* fl = wsf + K * 256 + (b << 1);
  if (tid == 0) {
    __hip_atomic_store(&fl[h], FLAG_MAGIC + K, __ATOMIC_RELEASE, __HIP_MEMORY_SCOPE_AGENT);
    while (__hip_atomic_load(&fl[h ^ 1], __ATOMIC_ACQUIRE, __HIP_MEMORY_SCOPE_AGENT)
           != FLAG_MAGIC + K)
      __builtin_amdgcn_s_sleep(1);
  }
  __syncthreads();
  const char* rb = bufk + (size_t)h * 16384 + (size_t)tid * 64;
  #pragma unroll
  for (int q = 0; q < 4; ++q) {
    float4 w = *(const float4*)(rb + q * 16);
    v2f z0, z1;
    z0.x = w.x; z0.y = w.y; z1.x = w.z; z1.y = w.w;
    z[M.rd[2 * q]]     = z0;
    z[M.rd[2 * q + 1]] = z1;
  }
}

template<int T>
__device__ __forceinline__ void step(v2f (&z)[8], int tid, int h, int b,
                                     char* wsd, int* wsf, char* buf) {
  if constexpr (exchq(T)) exch<T>(z, tid, h, b, wsd, wsf);
  else                    restL<T>(z, tid, buf);
}

template<int L>
__device__ __forceinline__ void layer(v2f (&z)[8], int tid, int h, int b,
                                      const v2f* ang, char* wsd, int* wsf, char* buf) {
  const int base = 48 * L;
  constexpr int P = 12 * L;
  gates<0>(z, ang, base);  step<P + 1>(z, tid, h, b, wsd, wsf, buf);
  gates<1>(z, ang, base);  step<P + 2>(z, tid, h, b, wsd, wsf, buf);
  gates<2>(z, ang, base);  step<P + 3>(z, tid, h, b, wsd, wsf, buf);
  gates<3>(z, ang, base);  step<P + 4>(z, tid, h, b, wsd, wsf, buf);
  gates<4>(z, ang, base);  step<P + 5>(z, tid, h, b, wsd, wsf, buf);
  gates<5>(z, ang, base);  step<P + 6>(z, tid, h, b, wsd, wsf, buf);
  gates<6>(z, ang, base);  step<P + 7>(z, tid, h, b, wsd, wsf, buf);
  gates<7>(z, ang, base);  step<P + 8>(z, tid, h, b, wsd, wsf, buf);
  gates<8>(z, ang, base);  step<P + 9>(z, tid, h, b, wsd, wsf, buf);
  gates<9>(z, ang, base);  step<P + 10>(z, tid, h, b, wsd, wsf, buf);
  gates<10>(z, ang, base); step<P + 11>(z, tid, h, b, wsd, wsf, buf);
  gates<11>(z, ang, base);
  if constexpr (L < 2) step<P + 12>(z, tid, h, b, wsd, wsf, buf);
}

__global__ __launch_bounds__(BLKT) void ansatz_kernel(
    const float* __restrict__ sre, const float* __restrict__ sim,
    const float* __restrict__ params, float* __restrict__ out,
    int* wsf, char* wsd) {

  __shared__ alignas(16) v2f bufs[2048];    // 16 KB restage buffer
  __shared__ v2f ang[NPAR];

  const int b   = blockIdx.x >> 1;
  const int h   = blockIdx.x & 1;
  const int tid = threadIdx.x;
  char* buf = (char*)bufs;

  if (tid < NPAR) {
    float s, c;
    sincosf(0.5f * params[b * NPAR + tid], &s, &c);
    v2f a; a.x = c; a.y = s;
    ang[tid] = a;
  }

  // ---- init gather directly in phase-1 (epoch 0) layout ----
  // roles: reg {11,0,1}, wav(tid6,7)={6,7}, blk=8(h), lanes {2,3,4,5,9,10}
  v2f z[8];
  {
    int base = ((tid & 1)  << 2) | ((tid & 2)  << 2) | ((tid & 4)  << 2) |
               ((tid & 8)  << 2) | ((tid & 16) << 5) | ((tid & 32) << 5) |
               ((tid & 64)) | ((tid & 128)) | (h << 8);
    // lanes: tid0->4, tid1->8, tid2->16, tid3->32, tid4->512, tid5->1024;
    // wav: tid6->64, tid7->128  (the shifts above implement exactly this)
    const float4* pr = (const float4*)(sre + (size_t)b * DIM + base);
    const float4* pi = (const float4*)(sim + (size_t)b * DIM + base);
    float4 f0 = pr[0], f1 = pr[512];     // +2048 floats
    float4 g0 = pi[0], g1 = pi[512];
    z[0].x = f0.x; z[0].y = g0.x;  z[2].x = f0.y; z[2].y = g0.y;
    z[4].x = f0.z; z[4].y = g0.z;  z[6].x = f0.w; z[6].y = g0.w;
    z[1].x = f1.x; z[1].y = g1.x;  z[3].x = f1.y; z[3].y = g1.y;
    z[5].x = f1.z; z[5].y = g1.z;  z[7].x = f1.w; z[7].y = g1.w;
  }
  __syncthreads();   // ang ready

  layer<0>(z, tid, h, b, ang, wsd, wsf, buf);
  layer<1>(z, tid, h, b, ang, wsd, wsf, buf);
  layer<2>(z, tid, h, b, ang, wsd, wsf, buf);

  // ---- final: cross-wave LDS restage (T=36) into output phase, then store --
  {
    constexpr TMapL M = AM.lt[36];
    constexpr int JS = M.js, JN = M.jn;
    unsigned acc = 0;
    #pragma unroll
    for (int i = 0; i < 8; ++i)
      acc ^= (unsigned)(-((tid >> i) & 1)) & M.pk[i];
    const unsigned bo = acc & 0xffffu;
    const unsigned bn = acc >> 16;
    __syncthreads();
    #pragma unroll
    for (int r = 0; r < 8; ++r) {
      if (r & (1 << JS)) continue;
      v2f z0 = z[r], z1 = z[r | (1 << JS)];
      float4 w; w.x = z0.x; w.y = z0.y; w.z = z1.x; w.w = z1.y;
      *(float4*)(buf + (bo ^ M.so[r])) = w;
    }
    __syncthreads();
    #pragma unroll
    for (int r = 0; r < 8; ++r) {
      if (r & (1 << JN)) continue;
      float4 w = *(const float4*)(buf + (bn ^ M.rn[r]));
      v2f z0, z1;
      z0.x = w.x; z0.y = w.y; z1.x = w.z; z1.y = w.w;
      z[r] = z0; z[r | (1 << JN)] = z1;
    }
  }
  // output roles: reg {0,1,2} (8 consecutive amps), lanes {3,4,5,6,7,11},
  // wav {9,10}, blk 8(h)
  {
    int base = ((tid & 1)  << 3) | ((tid & 2)  << 3) | ((tid & 4)  << 3) |
               ((tid & 8)  << 3) | ((tid & 16) << 3) | ((tid & 32) << 6) |
               ((tid & 64) << 3) | ((tid & 128) << 3) | (h << 8);
    // lanes: tid0->8, tid1->16, tid2->32, tid3->64, tid4->128, tid5->2048;
    // wav: tid6->512, tid7->1024
    v2f* o2 = (v2f*)out + (size_t)b * DIM + base;
    #pragma unroll
    for (int r = 0; r < 8; r += 2) {
      float4 w;
      w.x = z[r].x;     w.y = z[r].y;
      w.z = z[r + 1].x; w.w = z[r + 1].y;
      *(float4*)(o2 + r) = w;
    }
  }
}

extern "C" void kernel_launch(void* const* d_in, const int* in_sizes, int n_in,
                              void* d_out, int out_size, void* d_ws, size_t ws_size,
                              hipStream_t stream) {
  const float* sre    = (const float*)d_in[0];
  const float* sim    = (const float*)d_in[1];
  const float* params = (const float*)d_in[2];
  float* out          = (float*)d_out;

  int* wsf  = (int*)d_ws;                 // 6*256 flags (poison-proof magic)
  char* wsd = (char*)d_ws + 8192;         // 6*128*32 KB exchange buffers

  const int B = in_sizes[0] / DIM;        // 128
  ansatz_kernel<<<2 * B, BLKT, 0, stream>>>(sre, sim, params, out, wsf, wsd);
}

// Round 9
// 78.936 us; speedup vs baseline: 4.5009x; 4.5009x over previous
//
#include <hip/hip_runtime.h>
#include <math.h>

#define DIM  4096
#define BLK  512            // 8 waves; 8 amplitudes (v2f) per thread; 2 waves/SIMD
#define NPAR 144

typedef float v2f __attribute__((ext_vector_type(2)));

// ---------------------------------------------------------------------------
// 12 canonical state bits per phase: 3 register bits, 3 wave bits (tid 6..8),
// 6 lane bits (tid 0..5, ascending canonical). Gates act on register-local
// bits. 12 epochs/layer (R6/R7-validated schedule). Wave-pinned runs ->
// wave-local restages (no barrier, no waitcnt: LDS is in-order per wave).
// Transition windows share one reg bit -> full b128 stash AND unstash.
// Angles live in lane-distributed VGPRs, fetched via v_readlane (no LDS).
// ---------------------------------------------------------------------------
struct Ph { int reg[3]; int wav[3]; };
struct TMap { unsigned pk[9]; unsigned short so[8]; unsigned short rn[8]; };

constexpr int REGS[12][3] = {
  {11,0,1},{1,2,3},{3,4,5},{5,6,7},{7,8,9},{9,10,11},
  {11,0,1},{9,10,11},{7,8,9},{5,6,7},{3,4,5},{1,2,3}};

constexpr Ph phaseAt(int i) {         // i = 0..37; 0/37 = global pseudo-phase
  Ph p = {};
  if (i == 0 || i == 37) {
    p.reg[0]=0; p.reg[1]=1; p.reg[2]=2;
    p.wav[0]=9; p.wav[1]=10; p.wav[2]=11;
    return p;
  }
  int e = (i - 1) % 12;
  for (int j = 0; j < 3; ++j) p.reg[j] = REGS[e][j];
  bool A = (e <= 2) || (e >= 10);     // pin {6,7,8} else {2,3,4}
  p.wav[0] = A ? 6 : 2; p.wav[1] = A ? 7 : 3; p.wav[2] = A ? 8 : 4;
  return p;
}
constexpr bool inArr(const int* a, int n, int b) {
  for (int i = 0; i < n; ++i) if (a[i] == b) return true;
  return false;
}
constexpr int idxOf3(const int* a, int v) {
  for (int j = 0; j < 3; ++j) if (a[j] == v) return j;
  return -1;
}
constexpr bool isLoc(int t) {
  if (t == 0 || t == 36) return false;
  Ph a = phaseAt(t), b = phaseAt(t + 1);
  return a.wav[0]==b.wav[0] && a.wav[1]==b.wav[1] && a.wav[2]==b.wav[2];
}
constexpr int bufIdx(int t) {
  int k = 0;
  for (int u = 0; u <= t; ++u) if (!isLoc(u)) ++k;
  return (k + 1) & 1;
}
constexpr int sharedBit(Ph o, Ph n) {
  for (int j = 0; j < 3; ++j) if (inArr(n.reg, 3, o.reg[j])) return o.reg[j];
  return -1;
}

struct BuildOut { TMap m; int js, jn; bool ok; };

// GF(2)-linear canonical->slot map (R7-validated). Row 0 = shared reg bit
// (b128 pairing both sides). Rows 1..3 = lane bits of both phases (bank-
// conflict-free b128). Local: wave bits -> rows 9..11 (private 4 KB/wave).
constexpr BuildOut buildT(Ph o, Ph n, bool local) {
  BuildOut R = {};
  R.ok = true;
  int s = sharedBit(o, n);
  if (s < 0) { R.ok = false; return R; }
  R.js = idxOf3(o.reg, s);
  R.jn = idxOf3(n.reg, s);
  if (R.js < 0 || R.jn < 0) { R.ok = false; return R; }
  bool lo[12] = {}, ln[12] = {};
  for (int b = 0; b < 12; ++b) {
    lo[b] = !inArr(o.reg,3,b) && !inArr(o.wav,3,b);
    ln[b] = !inArr(n.reg,3,b) && !inArr(n.wav,3,b);
  }
  int col[12] = {};
  bool uo[12] = {}, un[12] = {}, consumed[12] = {};
  col[s] = 1; consumed[s] = true;
  int row = 1;
  for (int b = 0; b < 12 && row < 4; ++b)
    if (lo[b] && ln[b] && !consumed[b]) { col[b] = 1 << row; uo[b]=un[b]=true; consumed[b]=true; ++row; }
  while (row < 4) {
    int a = -1, c = -1;
    for (int b = 0; b < 12; ++b) if (lo[b] && !uo[b] && !consumed[b]) { a = b; break; }
    for (int b = 0; b < 12; ++b) if (ln[b] && !un[b] && !consumed[b] && b != a) { c = b; break; }
    if (a < 0 || c < 0) { R.ok = false; return R; }
    col[a] |= 1 << row; col[c] |= 1 << row;
    uo[a]=true; un[c]=true; consumed[c]=true;     // a still needs an identity row
    ++row;
  }
  if (local) {
    for (int i = 0; i < 3; ++i) {
      if (consumed[o.wav[i]]) { R.ok = false; return R; }
      col[o.wav[i]] |= 1 << (9 + i);
      consumed[o.wav[i]] = true;
    }
    int rr = 4;
    for (int b = 0; b < 12; ++b) if (!consumed[b]) { col[b] |= 1 << rr; ++rr; }
    if (rr != 9) { R.ok = false; return R; }
  } else {
    int rr = 4;
    for (int b = 0; b < 12; ++b) if (!consumed[b]) { col[b] |= 1 << rr; ++rr; }
    if (rr != 12) { R.ok = false; return R; }
  }
  {                                     // rank-12 invertibility over GF(2)
    int pv[12] = {}, pb[12] = {};
    int nr = 0;
    for (int b = 0; b < 12; ++b) {
      int v = col[b];
      for (int k = 0; k < nr; ++k) if (v & pb[k]) v ^= pv[k];
      if (v) { pb[nr] = v & (-v); pv[nr] = v; ++nr; }
    }
    if (nr != 12) { R.ok = false; return R; }
  }
  int Lo[6] = {}, Ln[6] = {};
  int i0 = 0, i1 = 0;
  for (int b = 0; b < 12; ++b) { if (lo[b]) Lo[i0++] = b; if (ln[b]) Ln[i1++] = b; }
  if (i0 != 6 || i1 != 6) { R.ok = false; return R; }
  for (int i = 0; i < 9; ++i) {
    unsigned po = (i < 6) ? (unsigned)col[Lo[i]] : (unsigned)col[o.wav[i-6]];
    unsigned pn = (i < 6) ? (unsigned)col[Ln[i]] : (unsigned)col[n.wav[i-6]];
    R.m.pk[i] = po | (pn << 16);
  }
  for (int r = 0; r < 8; ++r) {
    int a = 0, c = 0;
    for (int j = 0; j < 3; ++j)
      if ((r >> j) & 1) { a ^= col[o.reg[j]]; c ^= col[n.reg[j]]; }
    R.m.so[r] = (unsigned short)(a * 8);
    R.m.rn[r] = (unsigned short)(c * 8);
  }
  return R;
}

struct AllT { TMap t[37]; bool loc[37]; int buf[37]; int js[37]; int jn[37]; bool ok; };
constexpr AllT buildAll() {
  AllT A = {};
  A.ok = true;
  for (int t = 0; t < 37; ++t) {
    BuildOut b = buildT(phaseAt(t), phaseAt(t + 1), isLoc(t));
    A.t[t] = b.m;
    A.ok = A.ok && b.ok;
    A.loc[t] = isLoc(t);
    A.buf[t] = bufIdx(t);
    A.js[t] = b.js;
    A.jn[t] = b.jn;
  }
  return A;
}
constexpr AllT AT = buildAll();
static_assert(AT.ok, "slot-map construction failed");

// ---------------- angle fetch via v_readlane --------------------------------
__device__ __forceinline__ float rlf(float v, int l) {
  return __int_as_float(__builtin_amdgcn_readlane(__float_as_int(v), l));
}
template<int AO>
__device__ __forceinline__ v2f angAt(const float (&ct)[3], const float (&st)[3]) {
  v2f a;
  a.x = rlf(ct[AO >> 6], AO & 63);
  a.y = rlf(st[AO >> 6], AO & 63);
  return a;
}

// ---------------- gates on the 8-amplitude register file --------------------
template<int J>
__device__ __forceinline__ void ry8(v2f (&z)[8], v2f a) {
  const float c = a.x, s = a.y;
  #pragma unroll
  for (int p = 0; p < 4; ++p) {
    const int r0 = ((p & ~((1 << J) - 1)) << 1) | (p & ((1 << J) - 1));
    const int r1 = r0 | (1 << J);
    v2f u = z[r0], v = z[r1];
    z[r0] = c * u - s * v;
    z[r1] = s * u + c * v;
  }
}
// CRX, off-diagonal -i*s (validated R1-R8)
template<int JC, int JT>
__device__ __forceinline__ void crx8(v2f (&z)[8], v2f a) {
  const float c = a.x, s = a.y;
  constexpr int MC = 1 << JC, MT = 1 << JT;
  constexpr int mlo = MC < MT ? MC : MT;
  constexpr int mhi = MC < MT ? MT : MC;
  #pragma unroll
  for (int p = 0; p < 2; ++p) {
    int q = ((p & ~(mlo - 1)) << 1) | (p & (mlo - 1));
    q = ((q & ~(mhi - 1)) << 1) | (q & (mhi - 1));
    const int r0 = q | MC, r1 = r0 | MT;
    v2f u = z[r0], v = z[r1];
    v2f n0, n1;
    n0.x = c * u.x + s * v.y;
    n0.y = c * u.y - s * v.x;
    n1.x = c * v.x + s * u.y;
    n1.y = c * v.y - s * u.x;
    z[r0] = n0; z[r1] = n1;
  }
}

// Epoch gate lists — verbatim from the R6/R7-validated schedule; angle index
// is compile-time (48*L + k) so the readlane lane is an immediate.
template<int E, int L>
__device__ __forceinline__ void gates(v2f (&z)[8], const float (&ct)[3], const float (&st)[3]) {
#define A(k) (angAt<48 * L + (k)>(ct, st))
  if constexpr (E == 0)      { ry8<0>(z,A(0));  ry8<1>(z,A(11)); ry8<2>(z,A(10));
                               crx8<1,0>(z,A(12)); crx8<2,1>(z,A(13)); }
  else if constexpr (E == 1) { ry8<1>(z,A(9));  ry8<2>(z,A(8));
                               crx8<1,0>(z,A(14)); crx8<2,1>(z,A(15)); }
  else if constexpr (E == 2) { ry8<1>(z,A(7));  ry8<2>(z,A(6));
                               crx8<1,0>(z,A(16)); crx8<2,1>(z,A(17)); }
  else if constexpr (E == 3) { ry8<1>(z,A(5));  ry8<2>(z,A(4));
                               crx8<1,0>(z,A(18)); crx8<2,1>(z,A(19)); }
  else if constexpr (E == 4) { ry8<1>(z,A(3));  ry8<2>(z,A(2));
                               crx8<1,0>(z,A(20)); crx8<2,1>(z,A(21)); }
  else if constexpr (E == 5) { ry8<1>(z,A(1));
                               crx8<1,0>(z,A(22)); crx8<2,1>(z,A(23)); }
  else if constexpr (E == 6) { ry8<0>(z,A(24)); ry8<1>(z,A(35)); ry8<2>(z,A(34));
                               crx8<1,2>(z,A(36)); crx8<0,1>(z,A(37)); }
  else if constexpr (E == 7) { ry8<0>(z,A(26)); ry8<1>(z,A(25));
                               crx8<1,2>(z,A(38)); crx8<0,1>(z,A(39)); }
  else if constexpr (E == 8) { ry8<0>(z,A(28)); ry8<1>(z,A(27));
                               crx8<1,2>(z,A(40)); crx8<0,1>(z,A(41)); }
  else if constexpr (E == 9) { ry8<0>(z,A(30)); ry8<1>(z,A(29));
                               crx8<1,2>(z,A(42)); crx8<0,1>(z,A(43)); }
  else if constexpr (E == 10){ ry8<0>(z,A(32)); ry8<1>(z,A(31));
                               crx8<1,2>(z,A(44)); crx8<0,1>(z,A(45)); }
  else                       { ry8<1>(z,A(33));
                               crx8<1,2>(z,A(46)); crx8<0,1>(z,A(47)); }
#undef A
}

template<int T>
__device__ __forceinline__ void restage(v2f (&z)[8], int tid, char* Lb, char* C0, char* C1) {
  constexpr bool LOC = AT.loc[T];
  constexpr int JS = AT.js[T], JN = AT.jn[T];
  char* buf = LOC ? Lb : (AT.buf[T] ? C1 : C0);
  unsigned acc = 0;
  #pragma unroll
  for (int i = 0; i < 9; ++i)
    acc ^= (unsigned)(-((tid >> i) & 1)) & AT.t[T].pk[i];
  const unsigned bo = (acc & 0xfffu) << 3;
  const unsigned bn = ((acc >> 16) & 0xfffu) << 3;
  // stash: 4 x ds_write_b128, pairing regs over the shared bit (slot bit 0)
  #pragma unroll
  for (int r = 0; r < 8; ++r) {
    if (r & (1 << JS)) continue;
    v2f z0 = z[r], z1 = z[r | (1 << JS)];
    float4 w; w.x = z0.x; w.y = z0.y; w.z = z1.x; w.w = z1.y;
    *(float4*)(buf + (bo ^ AT.t[T].so[r])) = w;
  }
  if (LOC) {
    // same-wave LDS ops are serviced in program order (R7-validated):
    // reads queue behind writes — only a compiler fence needed.
    asm volatile("" ::: "memory");
  } else {
    __syncthreads();
  }
  // unstash: 4 x ds_read_b128
  #pragma unroll
  for (int r = 0; r < 8; ++r) {
    if (r & (1 << JN)) continue;
    float4 w = *(const float4*)(buf + (bn ^ AT.t[T].rn[r]));
    v2f z0, z1;
    z0.x = w.x; z0.y = w.y;
    z1.x = w.z; z1.y = w.w;
    z[r] = z0;
    z[r | (1 << JN)] = z1;
  }
}

template<int L>
__device__ __forceinline__ void layer(v2f (&z)[8], int tid,
                                      const float (&ct)[3], const float (&st)[3],
                                      char* Lb, char* C0, char* C1) {
  gates<0, L>(z, ct, st);  restage<12*L + 1>(z, tid, Lb, C0, C1);
  gates<1, L>(z, ct, st);  restage<12*L + 2>(z, tid, Lb, C0, C1);
  gates<2, L>(z, ct, st);  restage<12*L + 3>(z, tid, Lb, C0, C1);
  gates<3, L>(z, ct, st);  restage<12*L + 4>(z, tid, Lb, C0, C1);
  gates<4, L>(z, ct, st);  restage<12*L + 5>(z, tid, Lb, C0, C1);
  gates<5, L>(z, ct, st);  restage<12*L + 6>(z, tid, Lb, C0, C1);
  gates<6, L>(z, ct, st);  restage<12*L + 7>(z, tid, Lb, C0, C1);
  gates<7, L>(z, ct, st);  restage<12*L + 8>(z, tid, Lb, C0, C1);
  gates<8, L>(z, ct, st);  restage<12*L + 9>(z, tid, Lb, C0, C1);
  gates<9, L>(z, ct, st);  restage<12*L + 10>(z, tid, Lb, C0, C1);
  gates<10, L>(z, ct, st); restage<12*L + 11>(z, tid, Lb, C0, C1);
  gates<11, L>(z, ct, st);
  if constexpr (L < 2) restage<12*L + 12>(z, tid, Lb, C0, C1);
}

__global__ __launch_bounds__(BLK) void ansatz_kernel(
    const float* __restrict__ sre, const float* __restrict__ sim,
    const float* __restrict__ params, float* __restrict__ out) {

  __shared__ alignas(16) v2f C0s[DIM], C1s[DIM], Ls[DIM];   // 3 x 32 KB

  const int b = blockIdx.x, tid = threadIdx.x;
  char* C0 = (char*)C0s;
  char* C1 = (char*)C1s;
  char* Lb = (char*)Ls;

  // ---- per-wave angle table in lane-distributed VGPRs (no LDS, no barrier)
  float ct[3], st[3];
  {
    const int lane = tid & 63;
    #pragma unroll
    for (int j = 0; j < 3; ++j) {
      int idx = lane + 64 * j;
      int ci = (idx < NPAR) ? idx : 0;
      float th = params[(size_t)b * NPAR + ci];
      sincosf(0.5f * th, &st[j], &ct[j]);
    }
  }

  // ---- init: direct gather in epoch-0 layout ----
  // epoch 0: reg {11,0,1} (r0<->bit11, r1<->bit0, r2<->bit1);
  // lanes tid0..5 -> bits {2,3,4,5,9,10}; waves tid6..8 -> bits {6,7,8}
  v2f z[8];
  {
    int base = ((tid & 15) << 2) | ((tid & 16) << 5) | ((tid & 32) << 5)
             | (tid & 64) | (tid & 128) | (tid & 256);
    const float4* pr = (const float4*)(sre + (size_t)b * DIM + base);
    const float4* pi = (const float4*)(sim + (size_t)b * DIM + base);
    float4 f0 = pr[0], f1 = pr[512];      // +2048 amps (bit 11)
    float4 g0 = pi[0], g1 = pi[512];
    z[0].x = f0.x; z[0].y = g0.x;  z[2].x = f0.y; z[2].y = g0.y;
    z[4].x = f0.z; z[4].y = g0.z;  z[6].x = f0.w; z[6].y = g0.w;
    z[1].x = f1.x; z[1].y = g1.x;  z[3].x = f1.y; z[3].y = g1.y;
    z[5].x = f1.z; z[5].y = g1.z;  z[7].x = f1.w; z[7].y = g1.w;
  }

  layer<0>(z, tid, ct, st, Lb, C0, C1);
  layer<1>(z, tid, ct, st, Lb, C0, C1);
  layer<2>(z, tid, ct, st, Lb, C0, C1);

  // ---- final: direct scatter store from epoch-11 layout ----
  // epoch 11: reg {1,2,3} (amp = base + 2*r); lanes tid0..5 -> bits
  // {0,4,5,9,10,11}; waves tid6..8 -> bits {6,7,8}
  {
    int base = (tid & 1) | ((tid & 2) << 3) | ((tid & 4) << 3)
             | ((tid & 8) << 6) | ((tid & 16) << 6) | ((tid & 32) << 6)
             | (tid & 64) | (tid & 128) | (tid & 256);
    v2f* o2 = (v2f*)out + (size_t)b * DIM + base;
    #pragma unroll
    for (int r = 0; r < 8; ++r)
      o2[2 * r] = z[r];
  }
}

extern "C" void kernel_launch(void* const* d_in, const int* in_sizes, int n_in,
                              void* d_out, int out_size, void* d_ws, size_t ws_size,
                              hipStream_t stream) {
  const float* sre    = (const float*)d_in[0];
  const float* sim    = (const float*)d_in[1];
  const float* params = (const float*)d_in[2];
  float* out          = (float*)d_out;

  const int B = in_sizes[0] / DIM;   // 128
  ansatz_kernel<<<B, BLK, 0, stream>>>(sre, sim, params, out);
}